// Round 1
// baseline (550.175 us; speedup 1.0000x reference)
//
#include <hip/hip_runtime.h>
#include <math.h>

// -------------------------------------------------------------------------
// k1: conv1 7x7 pad3 (12->64) + bias + ReLU + maxpool2x2  -> pooled[8][64][64][64]
// grid 256 = 8 batch x 16 tiles(32x32 conv px) x 2 oc-groups(32 oc)
// per thread: 4x4 conv px x 8 oc = 128 accumulators
// -------------------------------------------------------------------------
__global__ __launch_bounds__(256, 1) void k_conv1_pool(
    const float* __restrict__ images, const float* __restrict__ w1,
    const float* __restrict__ b1, float* __restrict__ pooled)
{
    __shared__ float in_t[12 * 38 * 42];   // row stride 42 (even, bank spread)
    __shared__ float w_t[588 * 32];        // [k=ic*49+ky*7+kx][oc_local]
    const int tid = threadIdx.x;
    const int bid = blockIdx.x;
    const int ocg  = bid & 1;
    const int tile = (bid >> 1) & 15;
    const int b    = bid >> 5;
    const int R0 = (tile >> 2) * 32;
    const int C0 = (tile & 3) * 32;
    const int ocBase = ocg * 32;

    // stage input tile (rows R0-3..R0+34, cols C0-3..C0+34), zero-padded
    for (int idx = tid; idx < 12 * 38 * 38; idx += 256) {
        int ic  = idx / 1444;
        int rem = idx - ic * 1444;
        int r   = rem / 38;
        int c   = rem - r * 38;
        int gr = R0 - 3 + r;
        int gc = C0 - 3 + c;
        float v = 0.0f;
        if ((unsigned)gr < 128u && (unsigned)gc < 128u)
            v = images[((b * 12 + ic) * 128 + gr) * 128 + gc];
        in_t[(ic * 38 + r) * 42 + c] = v;
    }
    // stage weights transposed to [k][oc_local]; LDS writes are linear (idx)
    for (int idx = tid; idx < 588 * 32; idx += 256) {
        int ocl = idx & 31;
        int k   = idx >> 5;
        w_t[idx] = w1[(ocBase + ocl) * 588 + k];
    }
    __syncthreads();

    const int wave = tid >> 6;            // oc sub-group (8 oc), uniform per wave
    const int p    = tid & 63;
    const int py0  = (p >> 3) * 4;        // thread's conv rows py0..py0+3
    const int px0  = (p & 7) * 4;         // cols px0..px0+3

    float acc[8][16];
    #pragma unroll
    for (int oc = 0; oc < 8; ++oc)
        #pragma unroll
        for (int q = 0; q < 16; ++q) acc[oc][q] = 0.0f;

    #pragma unroll 1
    for (int ic = 0; ic < 12; ++ic) {
        #pragma unroll 1
        for (int ky = 0; ky < 7; ++ky) {
            float f[4][10];
            #pragma unroll
            for (int i = 0; i < 4; ++i) {
                const float2* rp = (const float2*)&in_t[(ic * 38 + py0 + i + ky) * 42 + px0];
                #pragma unroll
                for (int j2 = 0; j2 < 5; ++j2) {
                    float2 t = rp[j2];
                    f[i][2 * j2]     = t.x;
                    f[i][2 * j2 + 1] = t.y;
                }
            }
            const float* wbase = &w_t[(ic * 49 + ky * 7) * 32 + wave * 8];
            #pragma unroll
            for (int kx = 0; kx < 7; ++kx) {
                const float4* wp = (const float4*)(wbase + kx * 32);  // broadcast reads
                float4 wa = wp[0];
                float4 wb = wp[1];
                float wv[8] = {wa.x, wa.y, wa.z, wa.w, wb.x, wb.y, wb.z, wb.w};
                #pragma unroll
                for (int oc = 0; oc < 8; ++oc)
                    #pragma unroll
                    for (int i = 0; i < 4; ++i)
                        #pragma unroll
                        for (int j = 0; j < 4; ++j)
                            acc[oc][i * 4 + j] = fmaf(f[i][j + kx], wv[oc], acc[oc][i * 4 + j]);
            }
        }
    }

    // bias + ReLU + 2x2 maxpool (max commutes with +bias; ReLU after)
    const int ph0 = (R0 + py0) >> 1;
    const int pw0 = (C0 + px0) >> 1;
    #pragma unroll
    for (int oc = 0; oc < 8; ++oc) {
        int ocf = ocBase + wave * 8 + oc;
        float bias = b1[ocf];
        #pragma unroll
        for (int i2 = 0; i2 < 2; ++i2) {
            float m0 = fmaxf(fmaxf(acc[oc][(2*i2)*4 + 0], acc[oc][(2*i2)*4 + 1]),
                             fmaxf(acc[oc][(2*i2+1)*4 + 0], acc[oc][(2*i2+1)*4 + 1]));
            float m1 = fmaxf(fmaxf(acc[oc][(2*i2)*4 + 2], acc[oc][(2*i2)*4 + 3]),
                             fmaxf(acc[oc][(2*i2+1)*4 + 2], acc[oc][(2*i2+1)*4 + 3]));
            float2 st;
            st.x = fmaxf(m0 + bias, 0.0f);
            st.y = fmaxf(m1 + bias, 0.0f);
            *(float2*)&pooled[((b * 64 + ocf) * 64 + ph0 + i2) * 64 + pw0] = st;
        }
    }
}

// -------------------------------------------------------------------------
// k2: conv2 3x3 pad1 (64->128) + bias + ReLU + position embedding -> x2[8][128][64][64]
// grid 256 = 8 batch x 4 tiles(32x32) x 8 oc-groups(16 oc); ic staged in 4 chunks of 16
// per thread: 4x4 px x 4 oc
// -------------------------------------------------------------------------
__global__ __launch_bounds__(256, 1) void k_conv2_emb(
    const float* __restrict__ pooled, const float* __restrict__ w2,
    const float* __restrict__ b2, const float* __restrict__ pew,
    const float* __restrict__ peb, float* __restrict__ x2)
{
    __shared__ float in_t[16 * 34 * 38];   // one ic-chunk, row stride 38
    __shared__ float w_t[576 * 16];        // [k=ic*9+kk][oc_local], all 64 ic
    const int tid = threadIdx.x;
    const int bid = blockIdx.x;
    const int ocg  = bid & 7;
    const int tile = (bid >> 3) & 3;
    const int b    = bid >> 5;
    const int R0 = (tile >> 1) * 32;
    const int C0 = (tile & 1) * 32;
    const int ocBase = ocg * 16;

    for (int idx = tid; idx < 576 * 16; idx += 256) {
        int ocl = idx & 15;
        int k   = idx >> 4;
        w_t[idx] = w2[(ocBase + ocl) * 576 + k];
    }

    const int wave = tid >> 6;
    const int p    = tid & 63;
    const int py0  = (p >> 3) * 4;
    const int px0  = (p & 7) * 4;

    float acc[4][16];
    #pragma unroll
    for (int oc = 0; oc < 4; ++oc)
        #pragma unroll
        for (int q = 0; q < 16; ++q) acc[oc][q] = 0.0f;

    #pragma unroll 1
    for (int chunk = 0; chunk < 4; ++chunk) {
        __syncthreads();
        for (int idx = tid; idx < 16 * 34 * 34; idx += 256) {
            int icl = idx / 1156;
            int rem = idx - icl * 1156;
            int r   = rem / 34;
            int c   = rem - r * 34;
            int gr = R0 - 1 + r;
            int gc = C0 - 1 + c;
            float v = 0.0f;
            if ((unsigned)gr < 64u && (unsigned)gc < 64u)
                v = pooled[((b * 64 + chunk * 16 + icl) * 64 + gr) * 64 + gc];
            in_t[(icl * 34 + r) * 38 + c] = v;
        }
        __syncthreads();
        #pragma unroll 1
        for (int icl = 0; icl < 16; ++icl) {
            float f[6][6];
            #pragma unroll
            for (int i = 0; i < 6; ++i) {
                const float2* rp = (const float2*)&in_t[(icl * 34 + py0 + i) * 38 + px0];
                #pragma unroll
                for (int j2 = 0; j2 < 3; ++j2) {
                    float2 t = rp[j2];
                    f[i][2 * j2]     = t.x;
                    f[i][2 * j2 + 1] = t.y;
                }
            }
            const float* wb = &w_t[((chunk * 16 + icl) * 9) * 16 + wave * 4];
            #pragma unroll
            for (int ky = 0; ky < 3; ++ky)
                #pragma unroll
                for (int kx = 0; kx < 3; ++kx) {
                    const float4 w4 = *(const float4*)(wb + (ky * 3 + kx) * 16);
                    float wv[4] = {w4.x, w4.y, w4.z, w4.w};
                    #pragma unroll
                    for (int oc = 0; oc < 4; ++oc)
                        #pragma unroll
                        for (int i = 0; i < 4; ++i)
                            #pragma unroll
                            for (int j = 0; j < 4; ++j)
                                acc[oc][i * 4 + j] = fmaf(f[i + ky][j + kx], wv[oc], acc[oc][i * 4 + j]);
                }
        }
    }

    // bias + ReLU + soft position embedding (grid value = i/63)
    const float inv63 = 1.0f / 63.0f;
    #pragma unroll
    for (int oc = 0; oc < 4; ++oc) {
        int ocf = ocBase + wave * 4 + oc;
        float bias = b2[ocf];
        float e0 = pew[ocf * 4 + 0], e1 = pew[ocf * 4 + 1];
        float e2 = pew[ocf * 4 + 2], e3 = pew[ocf * 4 + 3];
        float pb = peb[ocf];
        #pragma unroll
        for (int i = 0; i < 4; ++i) {
            int gh = R0 + py0 + i;
            float y = (float)gh * inv63;
            float rowc = pb + y * e0 + (1.0f - y) * e2;
            float4 st;
            float v[4];
            #pragma unroll
            for (int j = 0; j < 4; ++j) {
                int gw = C0 + px0 + j;
                float x = (float)gw * inv63;
                float emb = rowc + x * e1 + (1.0f - x) * e3;
                v[j] = fmaxf(acc[oc][i * 4 + j] + bias, 0.0f) + emb;
            }
            st.x = v[0]; st.y = v[1]; st.z = v[2]; st.w = v[3];
            *(float4*)&x2[((b * 128 + ocf) * 64 + gh) * 64 + C0 + px0] = st;
        }
    }
}

// -------------------------------------------------------------------------
// k3: masked spatial max partials. grid 256 = 8 b x 8 obj-groups(4 obj) x 4 px-quarters
// masks = rois[:, :, ::2, ::2]; exact semantics: max over px of x * m (m in {0,1})
// -------------------------------------------------------------------------
__global__ __launch_bounds__(256, 1) void k_roi(
    const float* __restrict__ x2, const int* __restrict__ rois,
    float* __restrict__ partial)
{
    __shared__ float mlds[4 * 1024];
    const int tid = threadIdx.x;
    const int bid = blockIdx.x;
    const int pe = bid & 3;          // pixel quarter (1024 px)
    const int og = (bid >> 2) & 7;   // object group (4 objects)
    const int b  = bid >> 5;

    for (int idx = tid; idx < 4 * 1024; idx += 256) {
        int ol = idx >> 10;
        int pp = idx & 1023;
        int px = pe * 1024 + pp;
        int h = px >> 6;
        int w = px & 63;
        mlds[idx] = rois[((b * 32 + og * 4 + ol) << 14) + (h << 8) + (w << 1)] ? 1.0f : 0.0f;
    }
    __syncthreads();

    const int wave = tid >> 6;
    const int lane = tid & 63;
    const int cBase = wave * 32;

    float acc[32][4];
    #pragma unroll
    for (int c = 0; c < 32; ++c)
        #pragma unroll
        for (int o = 0; o < 4; ++o) acc[c][o] = -INFINITY;

    #pragma unroll 1
    for (int step = 0; step < 16; ++step) {
        int pp = (step << 6) + lane;
        float m0 = mlds[pp];
        float m1 = mlds[1024 + pp];
        float m2 = mlds[2048 + pp];
        float m3 = mlds[3072 + pp];
        const float* xb = &x2[(b * 128 + cBase) * 4096 + pe * 1024 + pp];
        #pragma unroll
        for (int c = 0; c < 32; ++c) {
            float x = xb[c * 4096];
            acc[c][0] = fmaxf(acc[c][0], x * m0);
            acc[c][1] = fmaxf(acc[c][1], x * m1);
            acc[c][2] = fmaxf(acc[c][2], x * m2);
            acc[c][3] = fmaxf(acc[c][3], x * m3);
        }
    }

    // 64-lane max reduce
    #pragma unroll
    for (int c = 0; c < 32; ++c)
        #pragma unroll
        for (int o = 0; o < 4; ++o) {
            float v = acc[c][o];
            #pragma unroll
            for (int m = 1; m < 64; m <<= 1)
                v = fmaxf(v, __shfl_xor(v, m, 64));
            acc[c][o] = v;
        }
    #pragma unroll
    for (int o = 0; o < 4; ++o) {
        if (lane == o) {
            #pragma unroll
            for (int c = 0; c < 32; ++c)
                partial[((b * 32 + og * 4 + o) * 4 + pe) * 128 + cBase + c] = acc[c][o];
        }
    }
}

// k4: reduce the 4 pixel-quarter partials -> out[8][32][128]
__global__ void k_reduce(const float* __restrict__ partial, float* __restrict__ out) {
    int idx = blockIdx.x * 256 + threadIdx.x;
    int c  = idx & 127;
    int bo = idx >> 7;
    float v =          partial[(bo * 4 + 0) * 128 + c];
    v = fmaxf(v, partial[(bo * 4 + 1) * 128 + c]);
    v = fmaxf(v, partial[(bo * 4 + 2) * 128 + c]);
    v = fmaxf(v, partial[(bo * 4 + 3) * 128 + c]);
    out[idx] = v;
}

extern "C" void kernel_launch(void* const* d_in, const int* in_sizes, int n_in,
                              void* d_out, int out_size, void* d_ws, size_t ws_size,
                              hipStream_t stream) {
    const float* images = (const float*)d_in[0];
    const int*   rois   = (const int*)d_in[1];
    // d_in[2] = gt_pos (unused: use_ground_truth_pos=False)
    const float* w1  = (const float*)d_in[3];
    const float* b1  = (const float*)d_in[4];
    const float* w2  = (const float*)d_in[5];
    const float* b2  = (const float*)d_in[6];
    const float* pew = (const float*)d_in[7];
    const float* peb = (const float*)d_in[8];
    float* out = (float*)d_out;

    float* pooled  = (float*)d_ws;                    //  8*64*64*64  f32 =  8.39 MB
    float* x2      = pooled + 8 * 64 * 64 * 64;       //  8*128*64*64 f32 = 16.78 MB
    float* partial = x2 + 8 * 128 * 64 * 64;          //  8*32*4*128  f32 =  0.52 MB

    k_conv1_pool<<<256, 256, 0, stream>>>(images, w1, b1, pooled);
    k_conv2_emb<<<256, 256, 0, stream>>>(pooled, w2, b2, pew, peb, x2);
    k_roi<<<256, 256, 0, stream>>>(x2, rois, partial);
    k_reduce<<<128, 256, 0, stream>>>(partial, out);
}

// Round 2
// 337.041 us; speedup vs baseline: 1.6324x; 1.6324x over previous
//
#include <hip/hip_runtime.h>
#include <math.h>

#define N_POOLED (8*64*64*64)
#define N_X2     (8*128*64*64)
#define N_PARTIAL (8*32*8*128)
#define N_WT1    (588*64)
#define N_WT2    (576*128)

// ---- k_wt: transpose weights to [k][oc] so conv kernels can s_load them ----
__global__ void k_wt(const float* __restrict__ w1, const float* __restrict__ w2,
                     float* __restrict__ wT1, float* __restrict__ wT2) {
    int idx = blockIdx.x * 256 + threadIdx.x;   // 435*256 = 111360 exact
    if (idx < 37632) {
        int k = idx >> 6, oc = idx & 63;
        wT1[idx] = w1[oc * 588 + k];
    } else {
        int j = idx - 37632;                    // < 73728
        int k = j >> 7, oc = j & 127;
        wT2[j] = w2[oc * 576 + k];
    }
}

// -------------------------------------------------------------------------
// k1: conv1 7x7 pad3 (12->64) + bias + ReLU + maxpool2x2 -> pooled[8][64][64][64]
// grid 1024 = b(8, low bits: XCD pin) x tile(64: 16x16 px) x ocg(2: 32 oc)
// per thread: 2x2 conv px (= 1 pooled px) x 8 oc. Weights via SGPR (s_load).
// -------------------------------------------------------------------------
__global__ __launch_bounds__(256, 4) void k_conv1_pool(
    const float* __restrict__ images, const float* __restrict__ wT1,
    const float* __restrict__ b1, float* __restrict__ pooled)
{
    __shared__ float in_t[12 * 22 * 26];   // row stride 26: bank spread
    const int tid = threadIdx.x;
    const int bid = blockIdx.x;
    const int b    = bid & 7;
    const int rest = bid >> 3;
    const int ocg  = rest & 1;
    const int tile = rest >> 1;            // 0..63
    const int R0 = (tile >> 3) * 16;
    const int C0 = (tile & 7) * 16;

    // stage input tile rows R0-3..R0+18, cols C0-3..C0+18 (22x22), zero-pad
    for (int idx = tid; idx < 12 * 22 * 22; idx += 256) {
        int ic  = idx / 484;
        int rem = idx - ic * 484;
        int r   = rem / 22;
        int c   = rem - r * 22;
        int gr = R0 - 3 + r, gc = C0 - 3 + c;
        float v = 0.0f;
        if ((unsigned)gr < 128u && (unsigned)gc < 128u)
            v = images[((b * 12 + ic) * 128 + gr) * 128 + gc];
        in_t[(ic * 22 + r) * 26 + c] = v;
    }
    __syncthreads();

    const int waveU = __builtin_amdgcn_readfirstlane(tid >> 6);
    const int lane  = tid & 63;
    const int py0   = (lane >> 3) * 2;
    const int px0   = (lane & 7) * 2;
    const int ocf0  = ocg * 32 + waveU * 8;

    float acc[8][4];
    #pragma unroll
    for (int oc = 0; oc < 8; ++oc)
        #pragma unroll
        for (int q = 0; q < 4; ++q) acc[oc][q] = 0.0f;

    #pragma unroll 1
    for (int ic = 0; ic < 12; ++ic) {
        const float* base = &in_t[ic * 22 * 26];
        float fr[2][8];
        // initial two rows (lds row r holds global row R0-3+r; out py uses rows py..py+7)
        #pragma unroll
        for (int h = 0; h < 2; ++h) {
            const float2* rp = (const float2*)&base[(py0 + h) * 26 + px0];
            #pragma unroll
            for (int j2 = 0; j2 < 4; ++j2) {
                float2 t = rp[j2];
                fr[h][2 * j2] = t.x; fr[h][2 * j2 + 1] = t.y;
            }
        }
        #pragma unroll
        for (int ky = 0; ky < 7; ++ky) {
            #pragma unroll
            for (int kx = 0; kx < 7; ++kx) {
                const float* wp = &wT1[(ic * 49 + ky * 7 + kx) * 64 + ocf0];  // uniform -> s_load
                #pragma unroll
                for (int oc = 0; oc < 8; ++oc) {
                    float w = wp[oc];
                    acc[oc][0] = fmaf(fr[ky & 1][kx],           w, acc[oc][0]);
                    acc[oc][1] = fmaf(fr[ky & 1][kx + 1],       w, acc[oc][1]);
                    acc[oc][2] = fmaf(fr[(ky + 1) & 1][kx],     w, acc[oc][2]);
                    acc[oc][3] = fmaf(fr[(ky + 1) & 1][kx + 1], w, acc[oc][3]);
                }
            }
            if (ky < 6) {  // roll: load row py0+ky+2 into the slot just freed
                const float2* rp = (const float2*)&base[(py0 + ky + 2) * 26 + px0];
                #pragma unroll
                for (int j2 = 0; j2 < 4; ++j2) {
                    float2 t = rp[j2];
                    fr[ky & 1][2 * j2] = t.x; fr[ky & 1][2 * j2 + 1] = t.y;
                }
            }
        }
    }

    // bias + ReLU + 2x2 maxpool: this thread's 2x2 conv px == one pooled px
    const int ph = (R0 + py0) >> 1;
    const int pw = (C0 + px0) >> 1;
    #pragma unroll
    for (int oc = 0; oc < 8; ++oc) {
        float bias = b1[ocf0 + oc];
        float m = fmaxf(fmaxf(acc[oc][0], acc[oc][1]), fmaxf(acc[oc][2], acc[oc][3]));
        pooled[((b * 64 + ocf0 + oc) * 64 + ph) * 64 + pw] = fmaxf(m + bias, 0.0f);
    }
}

// -------------------------------------------------------------------------
// k2: conv2 3x3 pad1 (64->128) + bias + ReLU + pos-emb -> x2[8][128][64][64]
// grid 512 = b(8) x tile(16: 16x16 px) x ocg(4: 32 oc); ic in 4 chunks of 16.
// per thread: 2x2 px x 8 oc; input frags double-buffered in regs.
// -------------------------------------------------------------------------
__global__ __launch_bounds__(256, 4) void k_conv2_emb(
    const float* __restrict__ pooled, const float* __restrict__ wT2,
    const float* __restrict__ b2, const float* __restrict__ pew,
    const float* __restrict__ peb, float* __restrict__ x2)
{
    __shared__ float in_t[16 * 18 * 22];   // one 16-ic chunk, row stride 22
    const int tid = threadIdx.x;
    const int bid = blockIdx.x;
    const int b    = bid & 7;
    const int rest = bid >> 3;
    const int ocg  = rest & 3;
    const int tile = rest >> 2;            // 0..15
    const int R0 = (tile >> 2) * 16;
    const int C0 = (tile & 3) * 16;

    const int waveU = __builtin_amdgcn_readfirstlane(tid >> 6);
    const int lane  = tid & 63;
    const int py0   = (lane >> 3) * 2;
    const int px0   = (lane & 7) * 2;
    const int ocf0  = ocg * 32 + waveU * 8;

    float acc[8][4];
    #pragma unroll
    for (int oc = 0; oc < 8; ++oc)
        #pragma unroll
        for (int q = 0; q < 4; ++q) acc[oc][q] = 0.0f;

    float fA[4][4], fB[4][4];

    #pragma unroll 1
    for (int chunk = 0; chunk < 4; ++chunk) {
        __syncthreads();
        for (int idx = tid; idx < 16 * 18 * 18; idx += 256) {
            int icl = idx / 324;
            int rem = idx - icl * 324;
            int r   = rem / 18;
            int c   = rem - r * 18;
            int gr = R0 - 1 + r, gc = C0 - 1 + c;
            float v = 0.0f;
            if ((unsigned)gr < 64u && (unsigned)gc < 64u)
                v = pooled[((b * 64 + chunk * 16 + icl) * 64 + gr) * 64 + gc];
            in_t[(icl * 18 + r) * 22 + c] = v;
        }
        __syncthreads();

#define LOADF(dst, ICL)                                                          \
        _Pragma("unroll")                                                        \
        for (int i = 0; i < 4; ++i) {                                            \
            const float2* rp = (const float2*)&in_t[((ICL) * 18 + py0 + i) * 22 + px0]; \
            float2 t0 = rp[0], t1 = rp[1];                                       \
            dst[i][0] = t0.x; dst[i][1] = t0.y; dst[i][2] = t1.x; dst[i][3] = t1.y; \
        }

#define FMABLK(src, ICL)                                                         \
        {                                                                        \
            const int ic_ = chunk * 16 + (ICL);                                  \
            _Pragma("unroll")                                                    \
            for (int ky = 0; ky < 3; ++ky)                                       \
            _Pragma("unroll")                                                    \
            for (int kx = 0; kx < 3; ++kx) {                                     \
                const float* wp = &wT2[(ic_ * 9 + ky * 3 + kx) * 128 + ocf0];    \
                _Pragma("unroll")                                                \
                for (int oc = 0; oc < 8; ++oc) {                                 \
                    float w = wp[oc];                                            \
                    acc[oc][0] = fmaf(src[ky][kx],         w, acc[oc][0]);       \
                    acc[oc][1] = fmaf(src[ky][kx + 1],     w, acc[oc][1]);       \
                    acc[oc][2] = fmaf(src[ky + 1][kx],     w, acc[oc][2]);       \
                    acc[oc][3] = fmaf(src[ky + 1][kx + 1], w, acc[oc][3]);       \
                }                                                                \
            }                                                                    \
        }

        LOADF(fA, 0)
        #pragma unroll 1
        for (int icl = 0; icl < 16; icl += 2) {
            LOADF(fB, icl + 1)
            FMABLK(fA, icl)
            if (icl + 2 < 16) { LOADF(fA, icl + 2) }
            FMABLK(fB, icl + 1)
        }
#undef LOADF
#undef FMABLK
    }

    // bias + ReLU + soft position embedding (grid value = i/63)
    const float inv63 = 1.0f / 63.0f;
    #pragma unroll
    for (int oc = 0; oc < 8; ++oc) {
        int ocf = ocf0 + oc;
        float bias = b2[ocf];
        float e0 = pew[ocf * 4 + 0], e1 = pew[ocf * 4 + 1];
        float e2 = pew[ocf * 4 + 2], e3 = pew[ocf * 4 + 3];
        float pb = peb[ocf];
        #pragma unroll
        for (int di = 0; di < 2; ++di) {
            int gh = R0 + py0 + di;
            float y = (float)gh * inv63;
            float rowc = pb + y * e0 + (1.0f - y) * e2;
            int gw = C0 + px0;
            float xq0 = (float)gw * inv63;
            float xq1 = (float)(gw + 1) * inv63;
            float2 st;
            st.x = fmaxf(acc[oc][di * 2 + 0] + bias, 0.0f) + rowc + xq0 * e1 + (1.0f - xq0) * e3;
            st.y = fmaxf(acc[oc][di * 2 + 1] + bias, 0.0f) + rowc + xq1 * e1 + (1.0f - xq1) * e3;
            *(float2*)&x2[((b * 128 + ocf) * 64 + gh) * 64 + gw] = st;
        }
    }
}

// -------------------------------------------------------------------------
// k3: masked spatial max partials.
// grid 1024 = b(8, XCD pin) x og(8: 4 obj) x pe(8: 512 px) x cg(2: 64 ch)
// -------------------------------------------------------------------------
__global__ __launch_bounds__(256, 4) void k_roi(
    const float* __restrict__ x2, const int* __restrict__ rois,
    float* __restrict__ partial)
{
    __shared__ float mlds[4 * 512];
    const int tid = threadIdx.x;
    const int bid = blockIdx.x;
    const int b    = bid & 7;
    const int rest = bid >> 3;
    const int og   = rest & 7;
    const int pe   = (rest >> 3) & 7;
    const int cg   = rest >> 6;

    for (int idx = tid; idx < 4 * 512; idx += 256) {
        int ol = idx >> 9;
        int pp = idx & 511;
        int px = pe * 512 + pp;
        int h = px >> 6, w = px & 63;
        mlds[idx] = rois[((b * 32 + og * 4 + ol) << 14) + (h << 8) + (w << 1)] ? 1.0f : 0.0f;
    }
    __syncthreads();

    const int waveU = __builtin_amdgcn_readfirstlane(tid >> 6);
    const int lane  = tid & 63;
    const int c0    = cg * 64 + waveU * 16;

    float acc[16][4];
    #pragma unroll
    for (int c = 0; c < 16; ++c)
        #pragma unroll
        for (int o = 0; o < 4; ++o) acc[c][o] = -INFINITY;

    #pragma unroll 1
    for (int step = 0; step < 8; ++step) {
        int pp = step * 64 + lane;
        float m0 = mlds[pp], m1 = mlds[512 + pp], m2 = mlds[1024 + pp], m3 = mlds[1536 + pp];
        const float* xb = &x2[(b * 128 + c0) * 4096 + pe * 512 + pp];
        #pragma unroll
        for (int c = 0; c < 16; ++c) {
            float x = xb[c * 4096];
            acc[c][0] = fmaxf(acc[c][0], x * m0);
            acc[c][1] = fmaxf(acc[c][1], x * m1);
            acc[c][2] = fmaxf(acc[c][2], x * m2);
            acc[c][3] = fmaxf(acc[c][3], x * m3);
        }
    }

    #pragma unroll
    for (int c = 0; c < 16; ++c)
        #pragma unroll
        for (int o = 0; o < 4; ++o) {
            float v = acc[c][o];
            #pragma unroll
            for (int m = 1; m < 64; m <<= 1)
                v = fmaxf(v, __shfl_xor(v, m, 64));
            if (lane == o * 16 + c)
                partial[((b * 32 + og * 4 + o) * 8 + pe) * 128 + c0 + c] = v;
        }
}

// k4: reduce the 8 pixel-chunk partials -> out[8][32][128]
__global__ void k_reduce(const float* __restrict__ partial, float* __restrict__ out) {
    int idx = blockIdx.x * 256 + threadIdx.x;   // 32768
    int c  = idx & 127;
    int bo = idx >> 7;
    float v = partial[bo * 8 * 128 + c];
    #pragma unroll
    for (int pe = 1; pe < 8; ++pe)
        v = fmaxf(v, partial[(bo * 8 + pe) * 128 + c]);
    out[idx] = v;
}

extern "C" void kernel_launch(void* const* d_in, const int* in_sizes, int n_in,
                              void* d_out, int out_size, void* d_ws, size_t ws_size,
                              hipStream_t stream) {
    const float* images = (const float*)d_in[0];
    const int*   rois   = (const int*)d_in[1];
    // d_in[2] = gt_pos (unused)
    const float* w1  = (const float*)d_in[3];
    const float* b1  = (const float*)d_in[4];
    const float* w2  = (const float*)d_in[5];
    const float* b2  = (const float*)d_in[6];
    const float* pew = (const float*)d_in[7];
    const float* peb = (const float*)d_in[8];
    float* out = (float*)d_out;

    float* pooled  = (float*)d_ws;
    float* x2      = pooled  + N_POOLED;
    float* partial = x2      + N_X2;
    float* wT1     = partial + N_PARTIAL;
    float* wT2     = wT1     + N_WT1;

    k_wt<<<435, 256, 0, stream>>>(w1, w2, wT1, wT2);
    k_conv1_pool<<<1024, 256, 0, stream>>>(images, wT1, b1, pooled);
    k_conv2_emb<<<512, 256, 0, stream>>>(pooled, wT2, b2, pew, peb, x2);
    k_roi<<<1024, 256, 0, stream>>>(x2, rois, partial);
    k_reduce<<<128, 256, 0, stream>>>(partial, out);
}

// Round 4
// 322.419 us; speedup vs baseline: 1.7064x; 1.0454x over previous
//
#include <hip/hip_runtime.h>
#include <math.h>

#define N_POOLED (8*64*64*64)
#define N_X2     (8*128*64*64)
#define N_PARTIAL (8*32*8*128)
#define N_WT1    (588*64)
#define N_WT2    (576*128)

// ---- k_wt: repack weights into per-wave contiguous slabs ----
// wT1: [ic][ky][gg(8 oc-grp)][kx*8+ocl]  (56 floats contiguous per (ic,ky,gg))
// wT2: [ic][g4(32 oc-grp)][tap*4+ocl]    (36 floats contiguous per (ic,g4))
__global__ void k_wt(const float* __restrict__ w1, const float* __restrict__ w2,
                     float* __restrict__ wT1, float* __restrict__ wT2) {
    int idx = blockIdx.x * 256 + threadIdx.x;   // 435*256 = 111360 exact
    if (idx < 37632) {
        int ocl = idx & 7;
        int t2 = idx >> 3;
        int kx = t2 % 7;
        int t3 = t2 / 7;
        int gg = t3 & 7;
        int t4 = t3 >> 3;
        int ky = t4 % 7;
        int ic = t4 / 7;
        wT1[idx] = w1[(gg * 8 + ocl) * 588 + ic * 49 + ky * 7 + kx];
    } else {
        int j = idx - 37632;                    // < 73728
        int ocl = j & 3;
        int t2 = j >> 2;
        int tap = t2 % 9;
        int t3 = t2 / 9;
        int g4 = t3 & 31;
        int ic = t3 >> 5;
        wT2[j] = w2[(g4 * 4 + ocl) * 576 + ic * 9 + tap];
    }
}

// -------------------------------------------------------------------------
// k1: conv1 7x7 pad3 (12->64) + bias + ReLU + maxpool2x2 -> pooled[8][64][64][64]
// grid 1024 = b(8, XCD pin) x ocg(2: 32 oc) x tile(64: 16x16 px)
// per thread: 2x2 conv px x 8 oc. fr[8][8] fully register-resident per ic;
// all ds_reads hoisted to ic-top (imm offsets); weights s_load contiguous 56f.
// -------------------------------------------------------------------------
__global__ __launch_bounds__(256, 4) void k_conv1_pool(
    const float* __restrict__ images, const float* __restrict__ wT1,
    const float* __restrict__ b1, float* __restrict__ pooled)
{
    __shared__ float in_t[12 * 22 * 24];   // row stride 24: quarter-balanced banks
    const int tid = threadIdx.x;
    const int bid = blockIdx.x;
    const int b    = bid & 7;
    const int rest = bid >> 3;
    const int ocg  = rest & 1;
    const int tile = rest >> 1;            // 0..63
    const int R0 = (tile >> 3) * 16;
    const int C0 = (tile & 7) * 16;

    // stage input tile rows R0-3..R0+18, cols C0-3..C0+18 (22x22), zero-pad
    for (int idx = tid; idx < 12 * 22 * 22; idx += 256) {
        int ic  = idx / 484;
        int rem = idx - ic * 484;
        int r   = rem / 22;
        int c   = rem - r * 22;
        int gr = R0 - 3 + r, gc = C0 - 3 + c;
        float v = 0.0f;
        if ((unsigned)gr < 128u && (unsigned)gc < 128u)
            v = images[((b * 12 + ic) * 128 + gr) * 128 + gc];
        in_t[(ic * 22 + r) * 24 + c] = v;
    }
    __syncthreads();

    const int waveU = __builtin_amdgcn_readfirstlane(tid >> 6);
    const int lane  = tid & 63;
    const int py0   = (lane >> 3) * 2;
    const int px0   = (lane & 7) * 2;
    const int ocf0  = ocg * 32 + waveU * 8;
    const int gg    = ocg * 4 + waveU;

    const float* p     = &in_t[py0 * 24 + px0];   // one base VGPR; rest imm offsets
    const float* wslab = &wT1[gg * 56];           // + (ic*7+ky)*448, uniform

    float acc[8][4];
    #pragma unroll
    for (int oc = 0; oc < 8; ++oc)
        #pragma unroll
        for (int q = 0; q < 4; ++q) acc[oc][q] = 0.0f;

    #pragma unroll 1
    for (int ic = 0; ic < 12; ++ic) {
        // all LDS reads for this ic up front: 32 x ds_read_b64, imm offsets
        float fr[8][8];
        #pragma unroll
        for (int h = 0; h < 8; ++h)
            #pragma unroll
            for (int j2 = 0; j2 < 4; ++j2) {
                float2 t = *(const float2*)(p + ic * 528 + h * 24 + 2 * j2);
                fr[h][2 * j2] = t.x; fr[h][2 * j2 + 1] = t.y;
            }
        #pragma unroll
        for (int ky = 0; ky < 7; ++ky) {
            const float* wl = wslab + (ic * 7 + ky) * 448;  // 56 contiguous floats
            #pragma unroll
            for (int kx = 0; kx < 7; ++kx) {
                #pragma unroll
                for (int oc = 0; oc < 8; ++oc) {
                    float w = wl[kx * 8 + oc];
                    acc[oc][0] = fmaf(fr[ky][kx],         w, acc[oc][0]);
                    acc[oc][1] = fmaf(fr[ky][kx + 1],     w, acc[oc][1]);
                    acc[oc][2] = fmaf(fr[ky + 1][kx],     w, acc[oc][2]);
                    acc[oc][3] = fmaf(fr[ky + 1][kx + 1], w, acc[oc][3]);
                }
            }
        }
    }

    // bias + ReLU + 2x2 maxpool: this thread's 2x2 conv px == one pooled px
    const int ph = (R0 + py0) >> 1;
    const int pw = (C0 + px0) >> 1;
    #pragma unroll
    for (int oc = 0; oc < 8; ++oc) {
        float bias = b1[ocf0 + oc];
        float m = fmaxf(fmaxf(acc[oc][0], acc[oc][1]), fmaxf(acc[oc][2], acc[oc][3]));
        pooled[((b * 64 + ocf0 + oc) * 64 + ph) * 64 + pw] = fmaxf(m + bias, 0.0f);
    }
}

// -------------------------------------------------------------------------
// k2: conv2 3x3 pad1 (64->128) + bias + ReLU + pos-emb -> x2[8][128][64][64]
// grid 1024 = b(8) x ocg(8: 16 oc) x tile(16: 16x16 px); ic in 4 chunks of 16.
// per thread: 2x2 px x 4 oc; fr[4][4] resident, ds hoisted, weights s_load 36f.
// -------------------------------------------------------------------------
__global__ __launch_bounds__(256, 4) void k_conv2_emb(
    const float* __restrict__ pooled, const float* __restrict__ wT2,
    const float* __restrict__ b2, const float* __restrict__ pew,
    const float* __restrict__ peb, float* __restrict__ x2)
{
    __shared__ float in_t[16 * 18 * 24];   // one 16-ic chunk, row stride 24
    const int tid = threadIdx.x;
    const int bid = blockIdx.x;
    const int b    = bid & 7;
    const int rest = bid >> 3;
    const int ocg  = rest & 7;
    const int tile = rest >> 3;            // 0..15
    const int R0 = (tile >> 2) * 16;
    const int C0 = (tile & 3) * 16;

    const int waveU = __builtin_amdgcn_readfirstlane(tid >> 6);
    const int lane  = tid & 63;
    const int py0   = (lane >> 3) * 2;
    const int px0   = (lane & 7) * 2;
    const int ocf0  = ocg * 16 + waveU * 4;
    const int g4    = ocg * 4 + waveU;

    const float* p     = &in_t[py0 * 24 + px0];
    const float* wslab = &wT2[g4 * 36];           // + ic*1152, uniform

    float acc[4][4];
    #pragma unroll
    for (int oc = 0; oc < 4; ++oc)
        #pragma unroll
        for (int q = 0; q < 4; ++q) acc[oc][q] = 0.0f;

    #pragma unroll 1
    for (int chunk = 0; chunk < 4; ++chunk) {
        __syncthreads();
        for (int idx = tid; idx < 16 * 18 * 18; idx += 256) {
            int icl = idx / 324;
            int rem = idx - icl * 324;
            int r   = rem / 18;
            int c   = rem - r * 18;
            int gr = R0 - 1 + r, gc = C0 - 1 + c;
            float v = 0.0f;
            if ((unsigned)gr < 64u && (unsigned)gc < 64u)
                v = pooled[((b * 64 + chunk * 16 + icl) * 64 + gr) * 64 + gc];
            in_t[(icl * 18 + r) * 24 + c] = v;
        }
        __syncthreads();

        #pragma unroll 1
        for (int icl = 0; icl < 16; ++icl) {
            float fr[4][4];
            #pragma unroll
            for (int h = 0; h < 4; ++h)
                #pragma unroll
                for (int j2 = 0; j2 < 2; ++j2) {
                    float2 t = *(const float2*)(p + icl * 432 + h * 24 + 2 * j2);
                    fr[h][2 * j2] = t.x; fr[h][2 * j2 + 1] = t.y;
                }
            const float* wl = wslab + (chunk * 16 + icl) * 1152;  // 36 contiguous
            #pragma unroll
            for (int ky = 0; ky < 3; ++ky)
                #pragma unroll
                for (int kx = 0; kx < 3; ++kx) {
                    #pragma unroll
                    for (int oc = 0; oc < 4; ++oc) {
                        float w = wl[(ky * 3 + kx) * 4 + oc];
                        acc[oc][0] = fmaf(fr[ky][kx],         w, acc[oc][0]);
                        acc[oc][1] = fmaf(fr[ky][kx + 1],     w, acc[oc][1]);
                        acc[oc][2] = fmaf(fr[ky + 1][kx],     w, acc[oc][2]);
                        acc[oc][3] = fmaf(fr[ky + 1][kx + 1], w, acc[oc][3]);
                    }
                }
        }
    }

    // bias + ReLU + soft position embedding (grid value = i/63)
    const float inv63 = 1.0f / 63.0f;
    #pragma unroll
    for (int oc = 0; oc < 4; ++oc) {
        int ocf = ocf0 + oc;
        float bias = b2[ocf];
        float e0 = pew[ocf * 4 + 0], e1 = pew[ocf * 4 + 1];
        float e2 = pew[ocf * 4 + 2], e3 = pew[ocf * 4 + 3];
        float pb = peb[ocf];
        #pragma unroll
        for (int di = 0; di < 2; ++di) {
            int gh = R0 + py0 + di;
            float y = (float)gh * inv63;
            float rowc = pb + y * e0 + (1.0f - y) * e2;
            int gw = C0 + px0;
            float xq0 = (float)gw * inv63;
            float xq1 = (float)(gw + 1) * inv63;
            float2 st;
            st.x = fmaxf(acc[oc][di * 2 + 0] + bias, 0.0f) + rowc + xq0 * e1 + (1.0f - xq0) * e3;
            st.y = fmaxf(acc[oc][di * 2 + 1] + bias, 0.0f) + rowc + xq1 * e1 + (1.0f - xq1) * e3;
            *(float2*)&x2[((b * 128 + ocf) * 64 + gh) * 64 + gw] = st;
        }
    }
}

// -------------------------------------------------------------------------
// k3: masked spatial max partials.
// grid 1024 = b(8, XCD pin) x og(8: 4 obj) x pe(8: 512 px) x cg(2: 64 ch)
// -------------------------------------------------------------------------
__global__ __launch_bounds__(256, 4) void k_roi(
    const float* __restrict__ x2, const int* __restrict__ rois,
    float* __restrict__ partial)
{
    __shared__ float mlds[4 * 512];
    const int tid = threadIdx.x;
    const int bid = blockIdx.x;
    const int b    = bid & 7;
    const int rest = bid >> 3;
    const int og   = rest & 7;
    const int pe   = (rest >> 3) & 7;
    const int cg   = rest >> 6;

    for (int idx = tid; idx < 4 * 512; idx += 256) {
        int ol = idx >> 9;
        int pp = idx & 511;
        int px = pe * 512 + pp;
        int h = px >> 6, w = px & 63;
        mlds[idx] = rois[((b * 32 + og * 4 + ol) << 14) + (h << 8) + (w << 1)] ? 1.0f : 0.0f;
    }
    __syncthreads();

    const int waveU = __builtin_amdgcn_readfirstlane(tid >> 6);
    const int lane  = tid & 63;
    const int c0    = cg * 64 + waveU * 16;

    float acc[16][4];
    #pragma unroll
    for (int c = 0; c < 16; ++c)
        #pragma unroll
        for (int o = 0; o < 4; ++o) acc[c][o] = -INFINITY;

    #pragma unroll 1
    for (int step = 0; step < 8; ++step) {
        int pp = step * 64 + lane;
        float m0 = mlds[pp], m1 = mlds[512 + pp], m2 = mlds[1024 + pp], m3 = mlds[1536 + pp];
        const float* xb = &x2[(b * 128 + c0) * 4096 + pe * 512 + pp];
        #pragma unroll
        for (int c = 0; c < 16; ++c) {
            float x = xb[c * 4096];
            acc[c][0] = fmaxf(acc[c][0], x * m0);
            acc[c][1] = fmaxf(acc[c][1], x * m1);
            acc[c][2] = fmaxf(acc[c][2], x * m2);
            acc[c][3] = fmaxf(acc[c][3], x * m3);
        }
    }

    #pragma unroll
    for (int c = 0; c < 16; ++c)
        #pragma unroll
        for (int o = 0; o < 4; ++o) {
            float v = acc[c][o];
            #pragma unroll
            for (int m = 1; m < 64; m <<= 1)
                v = fmaxf(v, __shfl_xor(v, m, 64));
            if (lane == o * 16 + c)
                partial[((b * 32 + og * 4 + o) * 8 + pe) * 128 + c0 + c] = v;
        }
}

// k4: reduce the 8 pixel-chunk partials -> out[8][32][128]
__global__ void k_reduce(const float* __restrict__ partial, float* __restrict__ out) {
    int idx = blockIdx.x * 256 + threadIdx.x;   // 32768
    int c  = idx & 127;
    int bo = idx >> 7;
    float v = partial[bo * 8 * 128 + c];
    #pragma unroll
    for (int pe = 1; pe < 8; ++pe)
        v = fmaxf(v, partial[(bo * 8 + pe) * 128 + c]);
    out[idx] = v;
}

extern "C" void kernel_launch(void* const* d_in, const int* in_sizes, int n_in,
                              void* d_out, int out_size, void* d_ws, size_t ws_size,
                              hipStream_t stream) {
    const float* images = (const float*)d_in[0];
    const int*   rois   = (const int*)d_in[1];
    // d_in[2] = gt_pos (unused)
    const float* w1  = (const float*)d_in[3];
    const float* b1  = (const float*)d_in[4];
    const float* w2  = (const float*)d_in[5];
    const float* b2  = (const float*)d_in[6];
    const float* pew = (const float*)d_in[7];
    const float* peb = (const float*)d_in[8];
    float* out = (float*)d_out;

    float* pooled  = (float*)d_ws;
    float* x2      = pooled  + N_POOLED;
    float* partial = x2      + N_X2;
    float* wT1     = partial + N_PARTIAL;
    float* wT2     = wT1     + N_WT1;

    k_wt<<<435, 256, 0, stream>>>(w1, w2, wT1, wT2);
    k_conv1_pool<<<1024, 256, 0, stream>>>(images, wT1, b1, pooled);
    k_conv2_emb<<<1024, 256, 0, stream>>>(pooled, wT2, b2, pew, peb, x2);
    k_roi<<<1024, 256, 0, stream>>>(x2, rois, partial);
    k_reduce<<<128, 256, 0, stream>>>(partial, out);
}

// Round 9
// 300.743 us; speedup vs baseline: 1.8294x; 1.0721x over previous
//
#include <hip/hip_runtime.h>
#include <math.h>

#define N_POOLED (8*64*64*64)
#define N_X2     (8*128*64*64)
#define N_PARTIAL (8*32*8*128)
#define N_WT1    (588*64)
#define N_WT2    (576*128)

// ---- k_wt: repack weights into per-wave contiguous slabs ----
// wT1: [ic][ky][gg(16 grp of 4oc)][kx*4+ocl]  (28 floats per (ic,ky,gg))
// wT2: [ic][g4(32 grp of 4oc)][tap*4+ocl]     (36 floats per (ic,g4))
__global__ void k_wt(const float* __restrict__ w1, const float* __restrict__ w2,
                     float* __restrict__ wT1, float* __restrict__ wT2) {
    int idx = blockIdx.x * 256 + threadIdx.x;   // 435*256 = 111360 exact
    if (idx < 37632) {
        int t = idx;
        int ocl = t & 3; t >>= 2;
        int kx = t % 7;  t /= 7;
        int gg = t & 15; t >>= 4;
        int ky = t % 7;
        int ic = t / 7;
        wT1[idx] = w1[(gg * 4 + ocl) * 588 + ic * 49 + ky * 7 + kx];
    } else {
        int j = idx - 37632;                    // < 73728
        int ocl = j & 3;
        int t2 = j >> 2;
        int tap = t2 % 9;
        int t3 = t2 / 9;
        int g4 = t3 & 31;
        int ic = t3 >> 5;
        wT2[j] = w2[(g4 * 4 + ocl) * 576 + ic * 9 + tap];
    }
}

// -------------------------------------------------------------------------
// k1: conv1 7x7 pad3 (12->64) + bias + ReLU + maxpool2x2 -> pooled[8][64][64][64]
// grid 2048 = b(8, XCD pin) x ocg(4: 16 oc) x tile(64: 16x16 px)
// 8 blocks/CU (launch_bounds(256,8), LDS 12.7KB: 6-ic stage x 2 phases).
// per thread: 2x2 conv px x 4 oc, rolling fr[2][8]; weights SGPR slabs.
// -------------------------------------------------------------------------
__global__ __launch_bounds__(256, 8) void k_conv1_pool(
    const float* __restrict__ images, const float* __restrict__ wT1,
    const float* __restrict__ b1, float* __restrict__ pooled)
{
    __shared__ float in_t[6 * 22 * 24];    // 6-ic chunk, row stride 24
    const int tid = threadIdx.x;
    const int bid = blockIdx.x;
    const int b    = bid & 7;
    const int rest = bid >> 3;
    const int ocg  = rest & 3;
    const int tile = rest >> 2;            // 0..63
    const int R0 = (tile >> 3) * 16;
    const int C0 = (tile & 7) * 16;

    const int waveU = __builtin_amdgcn_readfirstlane(tid >> 6);
    const int lane  = tid & 63;
    const int py0   = (lane >> 3) * 2;
    const int px0   = (lane & 7) * 2;
    const int ocf0  = ocg * 16 + waveU * 4;
    const int gg    = ocg * 4 + waveU;     // 0..15

    const float* p     = &in_t[py0 * 24 + px0];
    const float* wslab = &wT1[gg * 28];    // + (ic*7+ky)*448, uniform

    float acc[4][4];
    #pragma unroll
    for (int oc = 0; oc < 4; ++oc)
        #pragma unroll
        for (int q = 0; q < 4; ++q) acc[oc][q] = 0.0f;

    #pragma unroll 1
    for (int phase = 0; phase < 2; ++phase) {
        if (phase) __syncthreads();        // compute of prev phase done
        // stage 6 ic: rows R0-3..R0+18, cols C0-3..C0+18 (22x22), zero-pad
        for (int idx = tid; idx < 6 * 22 * 22; idx += 256) {
            int icl = idx / 484;
            int rem = idx - icl * 484;
            int r   = rem / 22;
            int c   = rem - r * 22;
            int gr = R0 - 3 + r, gc = C0 - 3 + c;
            float v = 0.0f;
            if ((unsigned)gr < 128u && (unsigned)gc < 128u)
                v = images[((b * 12 + phase * 6 + icl) * 128 + gr) * 128 + gc];
            in_t[(icl * 22 + r) * 24 + c] = v;
        }
        __syncthreads();

        #pragma unroll 1
        for (int icl = 0; icl < 6; ++icl) {
            const int ic = phase * 6 + icl;
            const float* base = p + icl * 528;       // 22*24
            float fr[2][8];
            #pragma unroll
            for (int h = 0; h < 2; ++h)
                #pragma unroll
                for (int j2 = 0; j2 < 4; ++j2) {
                    float2 t = *(const float2*)(base + h * 24 + 2 * j2);
                    fr[h][2 * j2] = t.x; fr[h][2 * j2 + 1] = t.y;
                }
            #pragma unroll
            for (int ky = 0; ky < 7; ++ky) {
                const float* wl = wslab + (ic * 7 + ky) * 448;   // 28 contiguous
                #pragma unroll
                for (int kx = 0; kx < 7; ++kx) {
                    #pragma unroll
                    for (int oc = 0; oc < 4; ++oc) {
                        float w = wl[kx * 4 + oc];
                        acc[oc][0] = fmaf(fr[ky & 1][kx],           w, acc[oc][0]);
                        acc[oc][1] = fmaf(fr[ky & 1][kx + 1],       w, acc[oc][1]);
                        acc[oc][2] = fmaf(fr[(ky + 1) & 1][kx],     w, acc[oc][2]);
                        acc[oc][3] = fmaf(fr[(ky + 1) & 1][kx + 1], w, acc[oc][3]);
                    }
                }
                if (ky < 6) {   // roll in row py0+ky+2
                    #pragma unroll
                    for (int j2 = 0; j2 < 4; ++j2) {
                        float2 t = *(const float2*)(base + (ky + 2) * 24 + 2 * j2);
                        fr[ky & 1][2 * j2] = t.x; fr[ky & 1][2 * j2 + 1] = t.y;
                    }
                }
            }
        }
    }

    // bias + ReLU + 2x2 maxpool: 2x2 conv px == one pooled px
    const int ph = (R0 + py0) >> 1;
    const int pw = (C0 + px0) >> 1;
    #pragma unroll
    for (int oc = 0; oc < 4; ++oc) {
        float bias = b1[ocf0 + oc];
        float m = fmaxf(fmaxf(acc[oc][0], acc[oc][1]), fmaxf(acc[oc][2], acc[oc][3]));
        pooled[((b * 64 + ocf0 + oc) * 64 + ph) * 64 + pw] = fmaxf(m + bias, 0.0f);
    }
}

// -------------------------------------------------------------------------
// k2: conv2 3x3 pad1 (64->128) + bias + ReLU + pos-emb -> x2[8][128][64][64]
// (unchanged from R4)
// -------------------------------------------------------------------------
__global__ __launch_bounds__(256, 4) void k_conv2_emb(
    const float* __restrict__ pooled, const float* __restrict__ wT2,
    const float* __restrict__ b2, const float* __restrict__ pew,
    const float* __restrict__ peb, float* __restrict__ x2)
{
    __shared__ float in_t[16 * 18 * 24];   // one 16-ic chunk, row stride 24
    const int tid = threadIdx.x;
    const int bid = blockIdx.x;
    const int b    = bid & 7;
    const int rest = bid >> 3;
    const int ocg  = rest & 7;
    const int tile = rest >> 3;            // 0..15
    const int R0 = (tile >> 2) * 16;
    const int C0 = (tile & 3) * 16;

    const int waveU = __builtin_amdgcn_readfirstlane(tid >> 6);
    const int lane  = tid & 63;
    const int py0   = (lane >> 3) * 2;
    const int px0   = (lane & 7) * 2;
    const int ocf0  = ocg * 16 + waveU * 4;
    const int g4    = ocg * 4 + waveU;

    const float* p     = &in_t[py0 * 24 + px0];
    const float* wslab = &wT2[g4 * 36];           // + ic*1152, uniform

    float acc[4][4];
    #pragma unroll
    for (int oc = 0; oc < 4; ++oc)
        #pragma unroll
        for (int q = 0; q < 4; ++q) acc[oc][q] = 0.0f;

    #pragma unroll 1
    for (int chunk = 0; chunk < 4; ++chunk) {
        __syncthreads();
        for (int idx = tid; idx < 16 * 18 * 18; idx += 256) {
            int icl = idx / 324;
            int rem = idx - icl * 324;
            int r   = rem / 18;
            int c   = rem - r * 18;
            int gr = R0 - 1 + r, gc = C0 - 1 + c;
            float v = 0.0f;
            if ((unsigned)gr < 64u && (unsigned)gc < 64u)
                v = pooled[((b * 64 + chunk * 16 + icl) * 64 + gr) * 64 + gc];
            in_t[(icl * 18 + r) * 24 + c] = v;
        }
        __syncthreads();

        #pragma unroll 1
        for (int icl = 0; icl < 16; ++icl) {
            float fr[4][4];
            #pragma unroll
            for (int h = 0; h < 4; ++h)
                #pragma unroll
                for (int j2 = 0; j2 < 2; ++j2) {
                    float2 t = *(const float2*)(p + icl * 432 + h * 24 + 2 * j2);
                    fr[h][2 * j2] = t.x; fr[h][2 * j2 + 1] = t.y;
                }
            const float* wl = wslab + (chunk * 16 + icl) * 1152;  // 36 contiguous
            #pragma unroll
            for (int ky = 0; ky < 3; ++ky)
                #pragma unroll
                for (int kx = 0; kx < 3; ++kx) {
                    #pragma unroll
                    for (int oc = 0; oc < 4; ++oc) {
                        float w = wl[(ky * 3 + kx) * 4 + oc];
                        acc[oc][0] = fmaf(fr[ky][kx],         w, acc[oc][0]);
                        acc[oc][1] = fmaf(fr[ky][kx + 1],     w, acc[oc][1]);
                        acc[oc][2] = fmaf(fr[ky + 1][kx],     w, acc[oc][2]);
                        acc[oc][3] = fmaf(fr[ky + 1][kx + 1], w, acc[oc][3]);
                    }
                }
        }
    }

    // bias + ReLU + soft position embedding (grid value = i/63)
    const float inv63 = 1.0f / 63.0f;
    #pragma unroll
    for (int oc = 0; oc < 4; ++oc) {
        int ocf = ocf0 + oc;
        float bias = b2[ocf];
        float e0 = pew[ocf * 4 + 0], e1 = pew[ocf * 4 + 1];
        float e2 = pew[ocf * 4 + 2], e3 = pew[ocf * 4 + 3];
        float pb = peb[ocf];
        #pragma unroll
        for (int di = 0; di < 2; ++di) {
            int gh = R0 + py0 + di;
            float y = (float)gh * inv63;
            float rowc = pb + y * e0 + (1.0f - y) * e2;
            int gw = C0 + px0;
            float xq0 = (float)gw * inv63;
            float xq1 = (float)(gw + 1) * inv63;
            float2 st;
            st.x = fmaxf(acc[oc][di * 2 + 0] + bias, 0.0f) + rowc + xq0 * e1 + (1.0f - xq0) * e3;
            st.y = fmaxf(acc[oc][di * 2 + 1] + bias, 0.0f) + rowc + xq1 * e1 + (1.0f - xq1) * e3;
            *(float2*)&x2[((b * 128 + ocf) * 64 + gh) * 64 + gw] = st;
        }
    }
}

// -------------------------------------------------------------------------
// k3: masked spatial max partials.
// grid 1024 = b(8) x og(2: 16 obj) x pe(8: 512 px) x cg(8: 16 ch)
// x2 read only 2x total (33 MB) vs 8x before; masks 16obj x 512px in LDS.
// per thread: 4 ch x 16 obj accumulators.
// -------------------------------------------------------------------------
__global__ __launch_bounds__(256, 4) void k_roi(
    const float* __restrict__ x2, const int* __restrict__ rois,
    float* __restrict__ partial)
{
    __shared__ float mlds[16 * 512];       // 32 KB
    const int tid = threadIdx.x;
    const int bid = blockIdx.x;
    const int b    = bid & 7;
    const int rest = bid >> 3;
    const int og   = rest & 1;
    const int pe   = (rest >> 1) & 7;
    const int cg   = rest >> 4;            // 0..7

    for (int idx = tid; idx < 16 * 512; idx += 256) {
        int ol = idx >> 9;
        int pp = idx & 511;
        int px = pe * 512 + pp;
        int h = px >> 6, w = px & 63;
        mlds[idx] = rois[((b * 32 + og * 16 + ol) << 14) + (h << 8) + (w << 1)] ? 1.0f : 0.0f;
    }
    __syncthreads();

    const int waveU = __builtin_amdgcn_readfirstlane(tid >> 6);
    const int lane  = tid & 63;
    const int c0    = cg * 16 + waveU * 4;

    float acc[4][16];
    #pragma unroll
    for (int c = 0; c < 4; ++c)
        #pragma unroll
        for (int o = 0; o < 16; ++o) acc[c][o] = -INFINITY;

    #pragma unroll 1
    for (int step = 0; step < 8; ++step) {
        int pp = step * 64 + lane;
        float m[16];
        #pragma unroll
        for (int o = 0; o < 16; ++o) m[o] = mlds[o * 512 + pp];
        const float* xb = &x2[(b * 128 + c0) * 4096 + pe * 512 + pp];
        #pragma unroll
        for (int c = 0; c < 4; ++c) {
            float x = xb[c * 4096];
            #pragma unroll
            for (int o = 0; o < 16; ++o)
                acc[c][o] = fmaxf(acc[c][o], x * m[o]);
        }
    }

    #pragma unroll
    for (int c = 0; c < 4; ++c)
        #pragma unroll
        for (int o = 0; o < 16; ++o) {
            float v = acc[c][o];
            #pragma unroll
            for (int mm = 1; mm < 64; mm <<= 1)
                v = fmaxf(v, __shfl_xor(v, mm, 64));
            if (lane == o * 4 + c)
                partial[((b * 32 + og * 16 + o) * 8 + pe) * 128 + c0 + c] = v;
        }
}

// k4: reduce the 8 pixel-chunk partials -> out[8][32][128]
__global__ void k_reduce(const float* __restrict__ partial, float* __restrict__ out) {
    int idx = blockIdx.x * 256 + threadIdx.x;   // 32768
    int c  = idx & 127;
    int bo = idx >> 7;
    float v = partial[bo * 8 * 128 + c];
    #pragma unroll
    for (int pe = 1; pe < 8; ++pe)
        v = fmaxf(v, partial[(bo * 8 + pe) * 128 + c]);
    out[idx] = v;
}

extern "C" void kernel_launch(void* const* d_in, const int* in_sizes, int n_in,
                              void* d_out, int out_size, void* d_ws, size_t ws_size,
                              hipStream_t stream) {
    const float* images = (const float*)d_in[0];
    const int*   rois   = (const int*)d_in[1];
    // d_in[2] = gt_pos (unused)
    const float* w1  = (const float*)d_in[3];
    const float* b1  = (const float*)d_in[4];
    const float* w2  = (const float*)d_in[5];
    const float* b2  = (const float*)d_in[6];
    const float* pew = (const float*)d_in[7];
    const float* peb = (const float*)d_in[8];
    float* out = (float*)d_out;

    float* pooled  = (float*)d_ws;
    float* x2      = pooled  + N_POOLED;
    float* partial = x2      + N_X2;
    float* wT1     = partial + N_PARTIAL;
    float* wT2     = wT1     + N_WT1;

    k_wt<<<435, 256, 0, stream>>>(w1, w2, wT1, wT2);
    k_conv1_pool<<<2048, 256, 0, stream>>>(images, wT1, b1, pooled);
    k_conv2_emb<<<1024, 256, 0, stream>>>(pooled, wT2, b2, pew, peb, x2);
    k_roi<<<1024, 256, 0, stream>>>(x2, rois, partial);
    k_reduce<<<128, 256, 0, stream>>>(partial, out);
}